// Round 8
// baseline (270.399 us; speedup 1.0000x reference)
//
#include <hip/hip_runtime.h>
#include <math.h>

typedef __attribute__((ext_vector_type(4))) int i32x4;
typedef __attribute__((ext_vector_type(16))) int i32x16;

namespace {
constexpr int N_ = 3136;
constexpr int M_ = N_ * 8;       // 25088 GEMM rows (n*8+z)
// ws layout (bytes)
constexpr size_t FIN_OFF   = 0;      // float[2]: amax, wmax
constexpr size_t AMAXP_OFF = 256;    // float[896] partials
constexpr size_t WMAXP_OFF = 4096;   // float[256] partials
constexpr size_t CHS_OFF   = 6144;   // float[512]
constexpr size_t ACT_OFF   = 32768;  // u8[25088][512]
constexpr size_t WGT_OFF   = ACT_OFF + (size_t)M_ * 512;  // u8[4096][512]
}

// offset=0 ALWAYS: the builtin's imm-offset arg is NOT applied to the global
// address for LDS-DMA on gfx950 (round-3 pass vs round-4 fail evidence).
__device__ __forceinline__ void gload(const char* g, char* l) {
  __builtin_amdgcn_global_load_lds(
      (const __attribute__((address_space(1))) char*)g,
      (__attribute__((address_space(3))) char*)l, 16, 0, 0);
}

// ---------- k1: amax partials (endpoint trick) + wmax partials + chs ----------
__global__ __launch_bounds__(256) void prep1_kernel(
    const float* __restrict__ x, const float* __restrict__ w,
    const float* __restrict__ gamma, const float* __restrict__ beta,
    const float* __restrict__ mean, const float* __restrict__ var,
    float* __restrict__ amaxp, float* __restrict__ wmaxp, float* __restrict__ chs) {
#pragma clang fp contract(off)
  __shared__ float red[4];
  const int bx = blockIdx.x, tid = threadIdx.x;
  if (bx < 896) {           // amax: thread = 28-float segment of one (b,c) row
    int id = bx * 256 + tid;
    int row = id / 28;
    int seg = id - row * 28;
    int c = row & 511;
    const float4* p = (const float4*)(x + (size_t)row * 784 + seg * 28);
    float mn = 1e30f, mx = -1e30f;
#pragma unroll
    for (int i = 0; i < 7; ++i) {
      float4 v = p[i];
      mn = fminf(mn, fminf(fminf(v.x, v.y), fminf(v.z, v.w)));
      mx = fmaxf(mx, fmaxf(fmaxf(v.x, v.y), fmaxf(v.z, v.w)));
    }
    float vf = var[c] + 1e-5f;
    float sc = (float)(1.0 / sqrt((double)vf)) * gamma[c];
    float f1 = (mn - mean[c]) * sc + beta[c];
    float f2 = (mx - mean[c]) * sc + beta[c];
    float m = fmaxf(fmaxf(f1, f2), 0.f);   // relu(affine) extrema at endpoints
#pragma unroll
    for (int o = 32; o > 0; o >>= 1) m = fmaxf(m, __shfl_down(m, o, 64));
    if ((tid & 63) == 0) red[tid >> 6] = m;
    __syncthreads();
    if (tid == 0) amaxp[bx] = fmaxf(fmaxf(red[0], red[1]), fmaxf(red[2], red[3]));
  } else if (bx < 1152) {   // wmax
    int id = (bx - 896) * 256 + tid;
    const float4* p = (const float4*)w + (size_t)id * 2;
    float4 v0 = p[0], v1 = p[1];
    float m = fmaxf(fmaxf(fmaxf(fabsf(v0.x), fabsf(v0.y)), fmaxf(fabsf(v0.z), fabsf(v0.w))),
                    fmaxf(fmaxf(fabsf(v1.x), fabsf(v1.y)), fmaxf(fabsf(v1.z), fabsf(v1.w))));
#pragma unroll
    for (int o = 32; o > 0; o >>= 1) m = fmaxf(m, __shfl_down(m, o, 64));
    if ((tid & 63) == 0) red[tid >> 6] = m;
    __syncthreads();
    if (tid == 0) wmaxp[bx - 896] = fmaxf(fmaxf(red[0], red[1]), fmaxf(red[2], red[3]));
  } else {                  // chs
    int c = (bx - 1152) * 256 + tid;
    float vf = var[c] + 1e-5f;
    chs[c] = (float)(1.0 / sqrt((double)vf)) * gamma[c];
  }
}

// ---------- k2: pack_x (bx<448) + pack_w (bx>=448) fused ----------
__global__ __launch_bounds__(256) void pack_xw_kernel(
    const float* __restrict__ x, const float* __restrict__ mean,
    const float* __restrict__ beta, const float* __restrict__ chs,
    const float* __restrict__ amaxp, const float* __restrict__ w,
    const float* __restrict__ wmaxp, unsigned* __restrict__ act,
    unsigned* __restrict__ wgt, float* __restrict__ fin) {
#pragma clang fp contract(off)
  const int bx = blockIdx.x, tid = threadIdx.x;
  if (bx < 448) {
    __shared__ float samax;
    __shared__ unsigned char sx[14 * 256];
    const int chalf = bx & 1;
    const int bh = bx >> 1;
    const int b = bh / 14, h2 = bh - b * 14;
    if (tid < 64) {
      float m = 0.f;
      for (int i = tid; i < 896; i += 64) m = fmaxf(m, amaxp[i]);
#pragma unroll
      for (int o = 32; o > 0; o >>= 1) m = fmaxf(m, __shfl_down(m, o, 64));
      if (tid == 0) {
        float a = fmaxf(m, 1e-8f);
        samax = a;
        if (bx == 0) fin[0] = a;
      }
    }
    __syncthreads();
    const float amax = samax;
    const int cbase = chalf * 256;
    for (int it = 0; it < 7; ++it) {
      int id = it * 256 + tid;
      int cl = id / 7, q = id - cl * 7;
      int c = cbase + cl;
      const float4 v = *(const float4*)(x + (size_t)(b * 512 + c) * 784 + h2 * 56 + q * 4);
      float sc = chs[c], mu = mean[c], be = beta[c];
      float f0 = fmaxf((v.x - mu) * sc + be, 0.f);
      int i0 = (int)rintf(fminf(fmaxf(f0 / amax, 0.f), 1.f) * 255.0f);
      float f2 = fmaxf((v.z - mu) * sc + be, 0.f);
      int i2 = (int)rintf(fminf(fmaxf(f2 / amax, 0.f), 1.f) * 255.0f);
      sx[(2 * q) * 256 + cl] = (unsigned char)i0;
      sx[(2 * q + 1) * 256 + cl] = (unsigned char)i2;
    }
    __syncthreads();
    const int nbase = b * 196 + h2 * 14;
    for (int it = 0; it < 4; ++it) {
      int id = it * 256 + tid;
      if (id < 896) {
        int cql = id & 63, w2 = id >> 6;
        unsigned v = *(const unsigned*)(sx + w2 * 256 + cql * 4);
        int n = nbase + w2;
        int cq = chalf * 64 + cql;
#pragma unroll
        for (int z = 0; z < 8; ++z)
          act[(size_t)(n * 8 + z) * 128 + cq] = (v >> z) & 0x01010101u;
      }
    }
  } else {
    __shared__ float swmax;
    const int bx2 = bx - 448;
    if (tid < 64) {
      float m = fmaxf(fmaxf(wmaxp[tid], wmaxp[tid + 64]),
                      fmaxf(wmaxp[tid + 128], wmaxp[tid + 192]));
#pragma unroll
      for (int o = 32; o > 0; o >>= 1) m = fmaxf(m, __shfl_down(m, o, 64));
      if (tid == 0) {
        float a = fmaxf(m, 1e-8f);
        swmax = a;
        if (bx2 == 0) fin[1] = a;
      }
    }
    __syncthreads();
    const float wmax = swmax;
    int t = bx2 * 256 + tid;
    int c16 = t & 31, k = (t >> 5) & 3, o = t >> 7;
    unsigned words[4];
#pragma unroll
    for (int q = 0; q < 4; ++q) {
      unsigned wd = 0;
#pragma unroll
      for (int j = 0; j < 4; ++j) {
        int c = c16 * 16 + q * 4 + j;
        float v = fminf(fmaxf(w[(size_t)o * 512 + c] / wmax, -1.f), 1.f);
        int wi = (int)rintf(v * 127.0f);
        unsigned wu = (unsigned)(wi + 128);
        unsigned cell = (wu >> (2 * k)) & 3u;
        wd |= (3u * cell + 1u) << (8 * j);
      }
      words[q] = wd;
    }
    *(uint4*)(wgt + ((size_t)(o * 4 + k) * 512 + c16 * 16) / 4) =
        make_uint4(words[0], words[1], words[2], words[3]);
  }
}

// ---------- k3: main. grid (32 cblk, 196 mblk), 128x128 tile, 2x2 wave tiling ----------
// B double-buffered in LDS (2x16KB); A double-buffered in registers (prefetched
// one full stage ahead); dummy byte-sums in-loop, quantize+shuffle in epilogue.
#define STAGEB(s_, p_) {                                  \
  char* lb = lds + (p_) * 16384 + ldst;                   \
  gload(gB + (s_) * 128 +  0, lb);                        \
  gload(gB + (s_) * 128 + 32, lb + 4096);                 \
  gload(gB + (s_) * 128 + 64, lb + 8192);                 \
  gload(gB + (s_) * 128 + 96, lb + 12288);                \
}

#define APREF(s_, p_) {                                                     \
  _Pragma("unroll")                                                         \
  for (int s2 = 0; s2 < 2; ++s2)                                            \
    _Pragma("unroll")                                                       \
    for (int j = 0; j < 4; ++j)                                             \
      av[p_][s2][j] = *(const i32x4*)(gA + s2 * 16384 + (s_) * 128 + j * 32); \
}

#define CSPASS(pb_, p_, cs_) {                                              \
  i32x16 c0, c1;                                                            \
  _Pragma("unroll")                                                         \
  for (int e = 0; e < 16; ++e) { c0[e] = 0; c1[e] = 0; }                    \
  _Pragma("unroll")                                                         \
  for (int j = 0; j < 4; ++j) {                                             \
    i32x4 bf = *(const i32x4*)(rB + (pb_) + j * 4096 + (cs_) * 512);        \
    c0 = __builtin_amdgcn_mfma_i32_32x32x32_i8(av[p_][0][j], bf, c0, 0, 0, 0); \
    c1 = __builtin_amdgcn_mfma_i32_32x32x32_i8(av[p_][1][j], bf, c1, 0, 0, 0); \
  }                                                                         \
  _Pragma("unroll")                                                         \
  for (int e = 0; e < 16; ++e) {                                            \
    unsigned q0q = (__umul24((unsigned)c0[e], 51610u) + 524288u) >> 20;     \
    acc[0][cs_][e >> 2] += (int)(q0q << shr[e & 3]);                        \
    unsigned q1q = (__umul24((unsigned)c1[e], 51610u) + 524288u) >> 20;     \
    acc[1][cs_][e >> 2] += (int)(q1q << shr[e & 3]);                        \
  }                                                                         \
}

// per-lane k-half byte sums for the dummy term (quantize deferred to epilogue)
#define XSUM(s_, p_) {                                                      \
  _Pragma("unroll")                                                         \
  for (int s2 = 0; s2 < 2; ++s2) {                                          \
    unsigned bs = 0;                                                        \
    _Pragma("unroll")                                                       \
    for (int j = 0; j < 4; ++j)                                             \
      bs += (unsigned)av[p_][s2][j].x + (unsigned)av[p_][s2][j].y +         \
            (unsigned)av[p_][s2][j].z + (unsigned)av[p_][s2][j].w;          \
    unsigned t = (bs & 0x00FF00FFu) + ((bs >> 8) & 0x00FF00FFu);            \
    xsp[s_][s2] = (t & 0xFFFFu) + (t >> 16);                                \
  }                                                                         \
}

#define COMPUTE(s_, p_) { XSUM(s_, p_) CSPASS((p_) * 16384, p_, 0) CSPASS((p_) * 16384, p_, 1) }

__global__ __launch_bounds__(256, 4) void shortcutq_main_kernel(
    const char* __restrict__ act, const char* __restrict__ wgt,
    const float* __restrict__ y, const float* __restrict__ fin,
    float* __restrict__ out) {
  __shared__ __align__(16) char lds[32768];
  const int tid = threadIdx.x;
  const int cblk = blockIdx.x;   // 32 (x-fastest: wgt slice hot in L2)
  const int mblk = blockIdx.y;   // 196
  const int lane = tid & 63, wv = tid >> 6;
  const int wm = wv >> 1, wn = wv & 1;

  const char* gA = act + (size_t)(mblk * 128 + wm * 64 + (lane & 31)) * 512 +
                   (lane >> 5) * 16;
  const char* gB = wgt + (size_t)(cblk * 128 + (tid & 127)) * 512 + (tid >> 7) * 16;
  const int ldst = tid * 16;
  const char* rB = lds + (lane >> 5) * 2048 + wn * 1024 + (lane & 31) * 16;

  const int shb = 4 * (lane >> 5) + 2 * (lane & 3);
  int shr[4] = {shb, shb + 1, shb + 2, shb + 3};
  const int zz = lane & 7;

  i32x4 av[2][2][4];          // [buf][s2][j]
  unsigned xsp[4][2];         // per-stage(g) per-s2 half-row byte sums
  int acc[2][2][4];           // [s2][cs][cc]
#pragma unroll
  for (int i = 0; i < 2; ++i)
#pragma unroll
    for (int j = 0; j < 2; ++j)
#pragma unroll
      for (int cc = 0; cc < 4; ++cc) acc[i][j][cc] = 0;

  APREF(0, 0)
  STAGEB(0, 0)
  __syncthreads();            // drains stage-0 DMA + A0 loads
  STAGEB(1, 1)                // in flight during stage-0 compute
  APREF(1, 1)
  COMPUTE(0, 0)
  __syncthreads();
  STAGEB(2, 0)
  APREF(2, 0)
  COMPUTE(1, 1)
  __syncthreads();
  STAGEB(3, 1)
  APREF(3, 1)
  COMPUTE(2, 0)
  __syncthreads();
  COMPUTE(3, 1)

  // ---- epilogue ----
  const float scale = (float)((128.0 * (3.0 + 1.0 / 3.0)) / 63.0) *
                      (fin[1] / 127.0f) * (fin[0] / 255.0f);
  // dummy: combine k-halves, quantize, weight by 2^z; then reduce over z
  int dacc[2] = {0, 0};
#pragma unroll
  for (int g = 0; g < 4; ++g)
#pragma unroll
    for (int s2 = 0; s2 < 2; ++s2) {
      unsigned xsf = xsp[g][s2] + (unsigned)__shfl_xor((int)xsp[g][s2], 32, 64);
      unsigned q0 = (__umul24(xsf, 51610u) + 524288u) >> 20;   // round(63x/1280)
      unsigned q3 = (__umul24(xsf, 361268u) + 524288u) >> 20;  // round(441x/1280)
      dacc[s2] += (int)((__umul24(q0, 21u) + (q3 << 6)) << zz);
    }
  int sums[2][2][4];
#pragma unroll
  for (int s2 = 0; s2 < 2; ++s2)
#pragma unroll
    for (int cs = 0; cs < 2; ++cs)
#pragma unroll
      for (int cc = 0; cc < 4; ++cc) {
        int v = acc[s2][cs][cc];
        v += __shfl_xor(v, 1, 64);
        v += __shfl_xor(v, 2, 64);
        v += __shfl_xor(v, 32, 64);
        sums[s2][cs][cc] = v;
      }
  int dn[2][4];
#pragma unroll
  for (int s2 = 0; s2 < 2; ++s2) {
    int v = dacc[s2];
    v += __shfl_xor(v, 1, 64);
    v += __shfl_xor(v, 2, 64);
    v += __shfl_xor(v, 4, 64);
#pragma unroll
    for (int cc = 0; cc < 4; ++cc) dn[s2][cc] = __shfl(v, cc * 8, 64);
  }
  if ((lane & 3) == 0 && lane < 32) {
    const int ol = lane >> 2;   // 0..7
#pragma unroll
    for (int s2 = 0; s2 < 2; ++s2)
#pragma unroll
      for (int cc = 0; cc < 4; ++cc) {
        int n = mblk * 16 + wm * 8 + s2 * 4 + cc;
        int b = n / 196, hw = n - b * 196;
#pragma unroll
        for (int cs = 0; cs < 2; ++cs) {
          int o = cblk * 32 + (wn * 2 + cs) * 8 + ol;
          size_t idx = ((size_t)(b * 1024 + o)) * 196 + hw;
          out[idx] = (float)(sums[s2][cs][cc] - dn[s2][cc]) * scale + y[idx];
        }
      }
  }
}

extern "C" void kernel_launch(void* const* d_in, const int* in_sizes, int n_in,
                              void* d_out, int out_size, void* d_ws, size_t ws_size,
                              hipStream_t stream) {
  const float* x     = (const float*)d_in[0];
  const float* y     = (const float*)d_in[1];
  const float* gamma = (const float*)d_in[2];
  const float* beta  = (const float*)d_in[3];
  const float* mean  = (const float*)d_in[4];
  const float* var   = (const float*)d_in[5];
  const float* w     = (const float*)d_in[6];
  float* out = (float*)d_out;

  char* wsb = (char*)d_ws;
  float* fin    = (float*)(wsb + FIN_OFF);
  float* amaxp  = (float*)(wsb + AMAXP_OFF);
  float* wmaxp  = (float*)(wsb + WMAXP_OFF);
  float* chs    = (float*)(wsb + CHS_OFF);
  char*  actb   = wsb + ACT_OFF;
  char*  wgtb   = wsb + WGT_OFF;

  hipLaunchKernelGGL(prep1_kernel, dim3(1154), dim3(256), 0, stream,
                     x, w, gamma, beta, mean, var, amaxp, wmaxp, chs);
  hipLaunchKernelGGL(pack_xw_kernel, dim3(960), dim3(256), 0, stream,
                     x, mean, beta, chs, amaxp, w, wmaxp,
                     (unsigned*)actb, (unsigned*)wgtb, fin);
  hipLaunchKernelGGL(shortcutq_main_kernel, dim3(32, 196), dim3(256), 0, stream,
                     actb, wgtb, y, fin, out);
}

// Round 9
// 220.818 us; speedup vs baseline: 1.2245x; 1.2245x over previous
//
#include <hip/hip_runtime.h>
#include <math.h>

typedef __attribute__((ext_vector_type(4))) int i32x4;
typedef __attribute__((ext_vector_type(16))) int i32x16;

namespace {
constexpr int N_ = 3136;
constexpr int M_ = N_ * 8;       // 25088 GEMM rows (n*8+z)
// ws layout (bytes)
constexpr size_t FIN_OFF   = 0;      // float[2]: amax, wmax
constexpr size_t AMAXP_OFF = 256;    // float[896] partials
constexpr size_t WMAXP_OFF = 4096;   // float[256] partials
constexpr size_t CHS_OFF   = 6144;   // float[512]
constexpr size_t ACT_OFF   = 32768;  // u8[25088][512]
constexpr size_t WGT_OFF   = ACT_OFF + (size_t)M_ * 512;  // u8[4096][512]
}

// offset=0 ALWAYS: the builtin's imm-offset arg is NOT applied to the global
// address for LDS-DMA on gfx950 (round-3 pass vs round-4 fail evidence).
__device__ __forceinline__ void gload(const char* g, char* l) {
  __builtin_amdgcn_global_load_lds(
      (const __attribute__((address_space(1))) char*)g,
      (__attribute__((address_space(3))) char*)l, 16, 0, 0);
}

// ---------- k1: amax partials (endpoint trick) + wmax partials + chs ----------
__global__ __launch_bounds__(256) void prep1_kernel(
    const float* __restrict__ x, const float* __restrict__ w,
    const float* __restrict__ gamma, const float* __restrict__ beta,
    const float* __restrict__ mean, const float* __restrict__ var,
    float* __restrict__ amaxp, float* __restrict__ wmaxp, float* __restrict__ chs) {
#pragma clang fp contract(off)
  __shared__ float red[4];
  const int bx = blockIdx.x, tid = threadIdx.x;
  if (bx < 896) {           // amax: thread = 28-float segment of one (b,c) row
    int id = bx * 256 + tid;
    int row = id / 28;
    int seg = id - row * 28;
    int c = row & 511;
    const float4* p = (const float4*)(x + (size_t)row * 784 + seg * 28);
    float mn = 1e30f, mx = -1e30f;
#pragma unroll
    for (int i = 0; i < 7; ++i) {
      float4 v = p[i];
      mn = fminf(mn, fminf(fminf(v.x, v.y), fminf(v.z, v.w)));
      mx = fmaxf(mx, fmaxf(fmaxf(v.x, v.y), fmaxf(v.z, v.w)));
    }
    float vf = var[c] + 1e-5f;
    float sc = (float)(1.0 / sqrt((double)vf)) * gamma[c];
    float f1 = (mn - mean[c]) * sc + beta[c];
    float f2 = (mx - mean[c]) * sc + beta[c];
    float m = fmaxf(fmaxf(f1, f2), 0.f);   // relu(affine) extrema at endpoints
#pragma unroll
    for (int o = 32; o > 0; o >>= 1) m = fmaxf(m, __shfl_down(m, o, 64));
    if ((tid & 63) == 0) red[tid >> 6] = m;
    __syncthreads();
    if (tid == 0) amaxp[bx] = fmaxf(fmaxf(red[0], red[1]), fmaxf(red[2], red[3]));
  } else if (bx < 1152) {   // wmax
    int id = (bx - 896) * 256 + tid;
    const float4* p = (const float4*)w + (size_t)id * 2;
    float4 v0 = p[0], v1 = p[1];
    float m = fmaxf(fmaxf(fmaxf(fabsf(v0.x), fabsf(v0.y)), fmaxf(fabsf(v0.z), fabsf(v0.w))),
                    fmaxf(fmaxf(fabsf(v1.x), fabsf(v1.y)), fmaxf(fabsf(v1.z), fabsf(v1.w))));
#pragma unroll
    for (int o = 32; o > 0; o >>= 1) m = fmaxf(m, __shfl_down(m, o, 64));
    if ((tid & 63) == 0) red[tid >> 6] = m;
    __syncthreads();
    if (tid == 0) wmaxp[bx - 896] = fmaxf(fmaxf(red[0], red[1]), fmaxf(red[2], red[3]));
  } else {                  // chs
    int c = (bx - 1152) * 256 + tid;
    float vf = var[c] + 1e-5f;
    chs[c] = (float)(1.0 / sqrt((double)vf)) * gamma[c];
  }
}

// ---------- k2: pack_x (bx<448) + pack_w (bx>=448) fused ----------
__global__ __launch_bounds__(256) void pack_xw_kernel(
    const float* __restrict__ x, const float* __restrict__ mean,
    const float* __restrict__ beta, const float* __restrict__ chs,
    const float* __restrict__ amaxp, const float* __restrict__ w,
    const float* __restrict__ wmaxp, unsigned* __restrict__ act,
    unsigned* __restrict__ wgt, float* __restrict__ fin) {
#pragma clang fp contract(off)
  const int bx = blockIdx.x, tid = threadIdx.x;
  if (bx < 448) {
    __shared__ float samax;
    __shared__ unsigned char sx[14 * 256];
    const int chalf = bx & 1;
    const int bh = bx >> 1;
    const int b = bh / 14, h2 = bh - b * 14;
    if (tid < 64) {
      float m = 0.f;
      for (int i = tid; i < 896; i += 64) m = fmaxf(m, amaxp[i]);
#pragma unroll
      for (int o = 32; o > 0; o >>= 1) m = fmaxf(m, __shfl_down(m, o, 64));
      if (tid == 0) {
        float a = fmaxf(m, 1e-8f);
        samax = a;
        if (bx == 0) fin[0] = a;
      }
    }
    __syncthreads();
    const float amax = samax;
    const int cbase = chalf * 256;
    for (int it = 0; it < 7; ++it) {
      int id = it * 256 + tid;
      int cl = id / 7, q = id - cl * 7;
      int c = cbase + cl;
      const float4 v = *(const float4*)(x + (size_t)(b * 512 + c) * 784 + h2 * 56 + q * 4);
      float sc = chs[c], mu = mean[c], be = beta[c];
      float f0 = fmaxf((v.x - mu) * sc + be, 0.f);
      int i0 = (int)rintf(fminf(fmaxf(f0 / amax, 0.f), 1.f) * 255.0f);
      float f2 = fmaxf((v.z - mu) * sc + be, 0.f);
      int i2 = (int)rintf(fminf(fmaxf(f2 / amax, 0.f), 1.f) * 255.0f);
      sx[(2 * q) * 256 + cl] = (unsigned char)i0;
      sx[(2 * q + 1) * 256 + cl] = (unsigned char)i2;
    }
    __syncthreads();
    const int nbase = b * 196 + h2 * 14;
    for (int it = 0; it < 4; ++it) {
      int id = it * 256 + tid;
      if (id < 896) {
        int cql = id & 63, w2 = id >> 6;
        unsigned v = *(const unsigned*)(sx + w2 * 256 + cql * 4);
        int n = nbase + w2;
        int cq = chalf * 64 + cql;
#pragma unroll
        for (int z = 0; z < 8; ++z)
          act[(size_t)(n * 8 + z) * 128 + cq] = (v >> z) & 0x01010101u;
      }
    }
  } else {
    __shared__ float swmax;
    const int bx2 = bx - 448;
    if (tid < 64) {
      float m = fmaxf(fmaxf(wmaxp[tid], wmaxp[tid + 64]),
                      fmaxf(wmaxp[tid + 128], wmaxp[tid + 192]));
#pragma unroll
      for (int o = 32; o > 0; o >>= 1) m = fmaxf(m, __shfl_down(m, o, 64));
      if (tid == 0) {
        float a = fmaxf(m, 1e-8f);
        swmax = a;
        if (bx2 == 0) fin[1] = a;
      }
    }
    __syncthreads();
    const float wmax = swmax;
    int t = bx2 * 256 + tid;
    int c16 = t & 31, k = (t >> 5) & 3, o = t >> 7;
    unsigned words[4];
#pragma unroll
    for (int q = 0; q < 4; ++q) {
      unsigned wd = 0;
#pragma unroll
      for (int j = 0; j < 4; ++j) {
        int c = c16 * 16 + q * 4 + j;
        float v = fminf(fmaxf(w[(size_t)o * 512 + c] / wmax, -1.f), 1.f);
        int wi = (int)rintf(v * 127.0f);
        unsigned wu = (unsigned)(wi + 128);
        unsigned cell = (wu >> (2 * k)) & 3u;
        wd |= (3u * cell + 1u) << (8 * j);
      }
      words[q] = wd;
    }
    *(uint4*)(wgt + ((size_t)(o * 4 + k) * 512 + c16 * 16) / 4) =
        make_uint4(words[0], words[1], words[2], words[3]);
  }
}

// ---------- k3: main. grid (64 cblk, 49 mslice). Persistent B in LDS (32 KB,
// loaded once, ONE barrier); 4 mblks x 4 g with zero internal barriers.
// Wave = 32 M-rows x 64 cols; A double-buffered in regs, one g ahead.

#define APREF(off_, p_) {                                   \
  av[p_][0] = *(const i32x4*)(gA + (off_) +  0);            \
  av[p_][1] = *(const i32x4*)(gA + (off_) + 32);            \
  av[p_][2] = *(const i32x4*)(gA + (off_) + 64);            \
  av[p_][3] = *(const i32x4*)(gA + (off_) + 96);            \
}

// per-lane half-row byte sum of buffer p_ -> xsp[g_]
#define XSUM(g_, p_) {                                      \
  unsigned bs = 0;                                          \
  _Pragma("unroll")                                         \
  for (int j = 0; j < 4; ++j)                               \
    bs += (unsigned)av[p_][j].x + (unsigned)av[p_][j].y +   \
          (unsigned)av[p_][j].z + (unsigned)av[p_][j].w;    \
  unsigned t = (bs & 0x00FF00FFu) + ((bs >> 8) & 0x00FF00FFu); \
  xsp[g_] = (t & 0xFFFFu) + (t >> 16);                      \
}

// one g: 8 MFMAs (2 independent chains), quantize 32 elems
#define GCOMP(g_, p_) {                                                       \
  i32x16 c0, c1;                                                              \
  _Pragma("unroll")                                                           \
  for (int e = 0; e < 16; ++e) { c0[e] = 0; c1[e] = 0; }                      \
  _Pragma("unroll")                                                           \
  for (int j = 0; j < 4; ++j) {                                               \
    i32x4 b0 = *(const i32x4*)(rB + (g_) * 8192 + j * 2048);                  \
    i32x4 b1 = *(const i32x4*)(rB + (g_) * 8192 + j * 2048 + 512);            \
    c0 = __builtin_amdgcn_mfma_i32_32x32x32_i8(av[p_][j], b0, c0, 0, 0, 0);   \
    c1 = __builtin_amdgcn_mfma_i32_32x32x32_i8(av[p_][j], b1, c1, 0, 0, 0);   \
  }                                                                           \
  _Pragma("unroll")                                                           \
  for (int e = 0; e < 16; ++e) {                                              \
    unsigned q0q = (__umul24((unsigned)c0[e], 51610u) + 524288u) >> 20;       \
    acc[0][e >> 2] += (int)(q0q << shr[e & 3]);                               \
    unsigned q1q = (__umul24((unsigned)c1[e], 51610u) + 524288u) >> 20;       \
    acc[1][e >> 2] += (int)(q1q << shr[e & 3]);                               \
  }                                                                           \
}

// unit u = i*4+g; prefetches unit u+1 (compile-time offsets), computes unit u
#define GUNIT(i_, g_, pref_) {                                                \
  const int p_ = ((i_) * 4 + (g_)) & 1;                                       \
  if (pref_) {                                                                \
    const int nu = (i_) * 4 + (g_) + 1;                                       \
    APREF((nu >> 2) * 65536 + (nu & 3) * 128, 1 - p_)                         \
  }                                                                           \
  XSUM(g_, p_)                                                                \
  GCOMP(g_, p_)                                                               \
}

#define MBLK_EPI(i_) {                                                        \
  int dacc = 0;                                                               \
  _Pragma("unroll")                                                           \
  for (int g = 0; g < 4; ++g) {                                               \
    unsigned xsf = xsp[g] + (unsigned)__shfl_xor((int)xsp[g], 32, 64);        \
    unsigned q0 = (__umul24(xsf, 51610u) + 524288u) >> 20;                    \
    unsigned q3 = (__umul24(xsf, 361268u) + 524288u) >> 20;                   \
    dacc += (int)((__umul24(q0, 21u) + (q3 << 6)) << zz);                     \
  }                                                                           \
  int sums[2][4];                                                             \
  _Pragma("unroll")                                                           \
  for (int cs = 0; cs < 2; ++cs)                                              \
    _Pragma("unroll")                                                         \
    for (int cc = 0; cc < 4; ++cc) {                                          \
      int v = acc[cs][cc];                                                    \
      v += __shfl_xor(v, 1, 64);                                              \
      v += __shfl_xor(v, 2, 64);                                              \
      v += __shfl_xor(v, 32, 64);                                             \
      sums[cs][cc] = v;                                                       \
      acc[cs][cc] = 0;                                                        \
    }                                                                         \
  int dv = dacc;                                                              \
  dv += __shfl_xor(dv, 1, 64);                                                \
  dv += __shfl_xor(dv, 2, 64);                                                \
  dv += __shfl_xor(dv, 4, 64);                                                \
  int dn[4];                                                                  \
  _Pragma("unroll")                                                           \
  for (int cc = 0; cc < 4; ++cc) dn[cc] = __shfl(dv, cc * 8, 64);             \
  if ((lane & 3) == 0 && lane < 32) {                                         \
    const int ol = lane >> 2;                                                 \
    _Pragma("unroll")                                                         \
    for (int cc = 0; cc < 4; ++cc) {                                          \
      int n = (mslice * 4 + (i_)) * 16 + wm * 4 + cc;                         \
      int b = n / 196, hw = n - b * 196;                                      \
      _Pragma("unroll")                                                       \
      for (int cs = 0; cs < 2; ++cs) {                                        \
        int o = cblk * 16 + cs * 8 + ol;                                      \
        size_t idx = ((size_t)(b * 1024 + o)) * 196 + hw;                     \
        out[idx] = (float)(sums[cs][cc] - dn[cc]) * scale + y[idx];           \
      }                                                                       \
    }                                                                         \
  }                                                                           \
}

#define MBLK(i_, last_) {                                                     \
  GUNIT(i_, 0, 1) GUNIT(i_, 1, 1) GUNIT(i_, 2, 1) GUNIT(i_, 3, !(last_))     \
  MBLK_EPI(i_)                                                                \
}

__global__ __launch_bounds__(256, 4) void shortcutq_main_kernel(
    const char* __restrict__ act, const char* __restrict__ wgt,
    const float* __restrict__ y, const float* __restrict__ fin,
    float* __restrict__ out) {
  __shared__ __align__(16) char lds[32768];   // B slice: [kidx(32)][row(64)][16B]
  const int tid = threadIdx.x;
  const int cblk = blockIdx.x;    // 64: 16 o x 4 k cols
  const int mslice = blockIdx.y;  // 49: 4 mblks each
  const int lane = tid & 63, wm = tid >> 6;

  // A stream base: wave wm owns rows wm*32..+32 of each mblk
  const char* gA = act + (size_t)(mslice * 4 * 128 + wm * 32 + (lane & 31)) * 512 +
                   (lane >> 5) * 16;
  // B: 8 DMA loads fill the full 64x512 slice
  const char* gB = wgt + (size_t)(cblk * 64 + (tid & 63)) * 512 + (tid >> 6) * 16;
  const char* rB = lds + (lane >> 5) * 1024 + (lane & 31) * 16;

  const int shb = 4 * (lane >> 5) + 2 * (lane & 3);
  int shr[4] = {shb, shb + 1, shb + 2, shb + 3};
  const int zz = lane & 7;

  i32x4 av[2][4];
  unsigned xsp[4];
  int acc[2][4];
#pragma unroll
  for (int cs = 0; cs < 2; ++cs)
#pragma unroll
    for (int cc = 0; cc < 4; ++cc) acc[cs][cc] = 0;

  APREF(0, 0)                      // unit 0 A-frags, in flight with B DMA
#pragma unroll
  for (int l = 0; l < 8; ++l)
    gload(gB + l * 64, lds + l * 4096 + tid * 16);
  __syncthreads();                 // the ONLY barrier

  const float scale = (float)((128.0 * (3.0 + 1.0 / 3.0)) / 63.0) *
                      (fin[1] / 127.0f) * (fin[0] / 255.0f);

  MBLK(0, 0) MBLK(1, 0) MBLK(2, 0) MBLK(3, 1)
}

extern "C" void kernel_launch(void* const* d_in, const int* in_sizes, int n_in,
                              void* d_out, int out_size, void* d_ws, size_t ws_size,
                              hipStream_t stream) {
  const float* x     = (const float*)d_in[0];
  const float* y     = (const float*)d_in[1];
  const float* gamma = (const float*)d_in[2];
  const float* beta  = (const float*)d_in[3];
  const float* mean  = (const float*)d_in[4];
  const float* var   = (const float*)d_in[5];
  const float* w     = (const float*)d_in[6];
  float* out = (float*)d_out;

  char* wsb = (char*)d_ws;
  float* fin    = (float*)(wsb + FIN_OFF);
  float* amaxp  = (float*)(wsb + AMAXP_OFF);
  float* wmaxp  = (float*)(wsb + WMAXP_OFF);
  float* chs    = (float*)(wsb + CHS_OFF);
  char*  actb   = wsb + ACT_OFF;
  char*  wgtb   = wsb + WGT_OFF;

  hipLaunchKernelGGL(prep1_kernel, dim3(1154), dim3(256), 0, stream,
                     x, w, gamma, beta, mean, var, amaxp, wmaxp, chs);
  hipLaunchKernelGGL(pack_xw_kernel, dim3(960), dim3(256), 0, stream,
                     x, mean, beta, chs, amaxp, w, wmaxp,
                     (unsigned*)actb, (unsigned*)wgtb, fin);
  hipLaunchKernelGGL(shortcutq_main_kernel, dim3(64, 49), dim3(256), 0, stream,
                     actb, wgtb, y, fin, out);
}